// Round 13
// baseline (149.835 us; speedup 1.0000x reference)
//
#include <hip/hip_runtime.h>

// Adaptive separable conv (SepConv): out[b,c,y,x] = sum_i sum_j inp[b,c,y+i,x+j]*v[b,i,y,x]*h[b,j,y,x]
// B=2,C=3,H=W=256,K=51. fp32 in/out. No MFMA path (per-pixel weights; no fp32 MFMA on CDNA4).
//
// R13: deconfound R10. R12 (z-split, 20-wave capacity) was FLAT vs R7 -> occupancy is not
// the lever. R10 (8-tap units, half the barrier-steps) lost 12% but ALSO dropped 12->8
// waves - confounded. This round: R12's geometry (z=half*6+bc i-split, 33-row inp slice,
// 15.3KB) + R10's step structure (8-tap h units = 2 chunks per barrier-step, 32KB dbuf)
// = half the barrier-steps AT 12 waves/CU (48.1KB -> 3 blocks/CU).
// Model being tested: each barrier-step carries ~400-600cy serial cost (post-barrier LDS
// burst + sync); 84 events/CU vs R7's 156 should reclaim ~10-15us.
// Keeps: R=8, TILE 64x8, 3-slot zero-mov windows, h row-rotation DMA layout, 1.25 ops/MAC,
// NS=4 wave-split of the half's 7 tap-blocks (2/2/2/1), launch_bounds(256,1), partials in
// d_ws summed by a tiny second kernel.

namespace {
constexpr int KK = 51;
constexpr int NB = 2;
constexpr int NC = 3;
constexpr int HH = 256;
constexpr int WW = 256;
constexpr int IN_H = HH + KK - 1;   // 306
constexpr int IN_W = WW + KK - 1;   // 306

constexpr int TILE_W = 64;          // output cols per block
constexpr int TILE_H = 8;           // output rows per block
constexpr int NTX = 8;              // threads along x (each covers R=8 outputs)
constexpr int R = 8;
constexpr int NTY = 8;
constexpr int NS = 4;
constexpr int NTHREADS = NTX * NTY * NS;   // 256
constexpr int HALO_W = TILE_W + KK - 1;    // 114
constexpr int LDS_W = 116;          // 114 valid + 2 slack
constexpr int LDS_H = 33;           // TILE_H-1 + 26 taps/half
constexpr int KSTRIDE = HH * WW;    // per-tap stride in v/h (65536)
constexpr int HCH  = 4 * TILE_H * TILE_W;  // 2048 floats per 4-tap chunk
constexpr int UNIT = 2 * HCH;              // 4096 floats per 8-tap stage unit (16KB)
constexpr int OUTN = NB * NC * HH * WW;    // 393216 floats per half-partial
}

__device__ __forceinline__ float fget(const float4 v, int i) {
  return (i == 0) ? v.x : (i == 1) ? v.y : (i == 2) ? v.z : v.w;
}

// One j-tap: t = sum_ib v[ib]*w[ib], acc += h*t. P = window phase, JJ = j within chunk.
template <int P, int JJ>
__device__ __forceinline__ void fma_jtap(const float4 (&v4)[4][2], const float4 (&w4)[4][3],
                                         const float4 ha, const float4 hb, float (&acc)[R]) {
#pragma unroll
  for (int rx = 0; rx < R; ++rx) {
    const int k  = rx + JJ;            // logical window index 0..10
    const int sl = (P + k / 4) % 3;    // physical slot
    const int cp = k & 3;
    const int vh = rx >> 2, vc = rx & 3;
    float tv = fget(v4[0][vh], vc) * fget(w4[0][sl], cp);
    tv = fmaf(fget(v4[1][vh], vc), fget(w4[1][sl], cp), tv);
    tv = fmaf(fget(v4[2][vh], vc), fget(w4[2][sl], cp), tv);
    tv = fmaf(fget(v4[3][vh], vc), fget(w4[3][sl], cp), tv);
    const float hv = (rx < 4) ? fget(ha, vc) : fget(hb, vc);
    acc[rx] = fmaf(hv, tv, acc[rx]);
  }
}

// Full chunk (4 j-taps) at phase P; h from LDS region hb (one 2048-float chunk);
// then refill the vacated window slot P from the inp tile.
template <int P>
__device__ __forceinline__ void full_chunk(const float4 (&v4)[4][2], float4 (&w4)[4][3],
                                           const int (&woff)[4], int wcol,
                                           const float* hb, int off0, int off1,
                                           float (&acc)[R], const float* smem) {
  const float4 h0a = *reinterpret_cast<const float4*>(hb + off0);
  const float4 h0b = *reinterpret_cast<const float4*>(hb + off1);
  const float4 h1a = *reinterpret_cast<const float4*>(hb + 512 + off0);
  const float4 h1b = *reinterpret_cast<const float4*>(hb + 512 + off1);
  fma_jtap<P, 0>(v4, w4, h0a, h0b, acc);
  const float4 h2a = *reinterpret_cast<const float4*>(hb + 1024 + off0);
  const float4 h2b = *reinterpret_cast<const float4*>(hb + 1024 + off1);
  fma_jtap<P, 1>(v4, w4, h1a, h1b, acc);
  const float4 h3a = *reinterpret_cast<const float4*>(hb + 1536 + off0);
  const float4 h3b = *reinterpret_cast<const float4*>(hb + 1536 + off1);
  fma_jtap<P, 2>(v4, w4, h2a, h2b, acc);
  fma_jtap<P, 3>(v4, w4, h3a, h3b, acc);
#pragma unroll
  for (int ib = 0; ib < 4; ++ib)
    w4[ib][P] = *reinterpret_cast<const float4*>(&smem[woff[ib] + wcol]);
}

__global__ __launch_bounds__(NTHREADS, 1)
void sepconv_kernel(
    const float* __restrict__ inp,
    const float* __restrict__ vert,
    const float* __restrict__ horiz,
    float* __restrict__ ws)
{
  __shared__ float lds[LDS_H * LDS_W];   // 15,312 B (inp slice; reused for reduction)
  __shared__ float hbuf[2 * UNIT];       // 32,768 B (two 8-tap h units)

  const int tid = threadIdx.x;
  const int tx  = tid & (NTX - 1);
  const int ty  = (tid >> 3) & (NTY - 1);
  const int s   = tid >> 6;                    // wave id: 0..3 (wave-uniform)

  const int x0 = blockIdx.x * TILE_W;
  const int y0 = blockIdx.y * TILE_H;
  const int zz = blockIdx.z;                   // 0..11
  const int bc = zz % (NB * NC);               // 0..5
  const int half = zz / (NB * NC);             // 0..1
  const int b  = bc / NC;
  const int c  = bc % NC;

  const int ROWBASE = half * 26;               // first i-tap of this half
  const int ROWMAX  = half ? 50 : 25;          // last real i-tap of this half

  // ---- Stage input slice: rows y0+ROWBASE .. +32 (clamped), 114 cols (float2).
  {
    const float* src = inp + (((size_t)(b * NC + c)) * IN_H) * IN_W + x0;
    constexpr int total2 = LDS_H * (HALO_W / 2);   // 33*57 = 1881
    for (int e = tid; e < total2; e += NTHREADS) {
      const int col2 = e % (HALO_W / 2);
      const int r    = e / (HALO_W / 2);
      const int gr   = min(y0 + ROWBASE + r, IN_H - 1);   // clamp (only masked taps touch it)
      const float2 v = *reinterpret_cast<const float2*>(src + (size_t)gr * IN_W + col2 * 2);
      float* dst = &lds[r * LDS_W + col2 * 2];
      dst[0] = v.x; dst[1] = v.y;
    }
  }

  // ---- h DMA mapping. Unit = 8 taps x 128 float4-slots. Physical slot p = r*256 + tid:
  // tap jj = p>>7 (0..7), row=(p&127)>>4, c4=p&15; slot holds global quad q=(c4-row)&15
  // (per-row rotation so the b128 read hits the 8-touch/bank floor).
  const float* hblk = horiz + (((size_t)b * KK) * HH + y0) * WW + x0;
  int jj_[4], goff_[4], ldso_[4];
#pragma unroll
  for (int r = 0; r < 4; ++r) {
    const int p   = r * 256 + tid;
    const int rem = p & 127;
    const int row = rem >> 4;
    const int c4  = rem & 15;
    const int q   = (c4 - row) & 15;
    jj_[r]   = p >> 7;
    goff_[r] = row * WW + q * 4;
    ldso_[r] = (r * 256 + (tid & ~63)) * 4;    // wave-uniform DMA dest base (floats)
  }
  auto stage_full = [&](int jbase, int bufn) {  // taps jbase..jbase+7 (<=47)
#pragma unroll
    for (int r = 0; r < 4; ++r) {
      const float* g = hblk + (size_t)(jbase + jj_[r]) * KSTRIDE + goff_[r];
      float* l = &hbuf[bufn * UNIT + ldso_[r]];
      __builtin_amdgcn_global_load_lds((const __attribute__((address_space(1))) void*)g,
                                       (__attribute__((address_space(3))) void*)l, 16, 0, 0);
    }
  };
  auto stage_half = [&](int bufn) {             // chunk 12 = taps 48..51 (51 clamped, unread)
#pragma unroll
    for (int r = 0; r < 2; ++r) {
      const int j  = 48 + jj_[r];
      const int jc = (j <= 50) ? j : 50;
      const float* g = hblk + (size_t)jc * KSTRIDE + goff_[r];
      float* l = &hbuf[bufn * UNIT + ldso_[r]];
      __builtin_amdgcn_global_load_lds((const __attribute__((address_space(1))) void*)g,
                                       (__attribute__((address_space(3))) void*)l, 16, 0, 0);
    }
  };

  // Prologue: unit 0 (chunks 0,1) -> buf0. Sync drains inp staging + DMA.
  stage_full(0, 0);
  __syncthreads();
  int buf = 0;
  int un  = 1;   // next unit (0..5 full, 6 = half), cycles per round

  auto stage_next = [&]() {
    if (un < 6) stage_full(8 * un, buf ^ 1);
    else        stage_half(buf ^ 1);
    un = (un == 6) ? 0 : un + 1;
  };

  const int lx = tx * R;                 // local LDS col base (32B aligned)
  const int xg = x0 + lx;
  const int yg = y0 + ty;

  // Rotated h read offsets (invariant): row ty, logical quads 2tx, 2tx+1.
  const int off0 = ty * 64 + ((2 * tx + ty) & 15) * 4;
  const int off1 = ty * 64 + ((2 * tx + 1 + ty) & 15) * 4;

  float acc[R];
#pragma unroll
  for (int rx = 0; rx < R; ++rx) acc[rx] = 0.f;

  // Deal 7 BI=4 tap-blocks (28 virtual taps of this half) to 4 waves: 2/2/2/1.
  const int blk0 = (s < 3) ? 2 * s : 6;
  const int nblk = (s < 3) ? 2 : 1;

  const float* vbase = vert + (((size_t)b * KK) * HH + yg) * WW + xg;

#pragma unroll 1
  for (int t = 0; t < 2; ++t) {          // uniform trip count for ALL waves (barriers!)
    const bool act = (t < nblk);
    float4 v4[4][2];
    float4 w4[4][3];
    int    woff[4];
    if (act) {
      const int ibase = ROWBASE + (blk0 + t) * 4;
#pragma unroll
      for (int ib = 0; ib < 4; ++ib) {
        const int iv = ibase + ib;                 // real tap index (may exceed ROWMAX)
        const int ic = (iv <= ROWMAX) ? iv : ROWMAX;
        float4 va = *reinterpret_cast<const float4*>(vbase + (size_t)ic * KSTRIDE);
        float4 vb = *reinterpret_cast<const float4*>(vbase + (size_t)ic * KSTRIDE + 4);
        if (iv > ROWMAX) { va = make_float4(0.f, 0.f, 0.f, 0.f); vb = va; }
        v4[ib][0] = va; v4[ib][1] = vb;
        woff[ib] = (ty + ic - ROWBASE) * LDS_W;    // row <= 32
        const float4* p = reinterpret_cast<const float4*>(&lds[woff[ib] + lx]);
        w4[ib][0] = p[0]; w4[ib][1] = p[1]; w4[ib][2] = p[2];
      }
    }

    // 6 full steps (2 chunks each), then the epilogue half-step. Phases advance 2/step.
#pragma unroll 1
    for (int h2 = 0; h2 < 2; ++h2) {
      const int cb = lx + 24 * h2 + 12;          // wcol base for this 6-chunk group
      const float* hb0;
      // step A: chunks 6h2+0 (P0), 6h2+1 (P1)
      stage_next();
      hb0 = hbuf + buf * UNIT;
      if (act) {
        full_chunk<0>(v4, w4, woff, cb + 0, hb0,       off0, off1, acc, lds);
        full_chunk<1>(v4, w4, woff, cb + 4, hb0 + HCH, off0, off1, acc, lds);
      }
      __syncthreads(); buf ^= 1;
      // step B: chunks 6h2+2 (P2), 6h2+3 (P0)
      stage_next();
      hb0 = hbuf + buf * UNIT;
      if (act) {
        full_chunk<2>(v4, w4, woff, cb + 8,  hb0,       off0, off1, acc, lds);
        full_chunk<0>(v4, w4, woff, cb + 12, hb0 + HCH, off0, off1, acc, lds);
      }
      __syncthreads(); buf ^= 1;
      // step C: chunks 6h2+4 (P1), 6h2+5 (P2)
      stage_next();
      hb0 = hbuf + buf * UNIT;
      if (act) {
        full_chunk<1>(v4, w4, woff, cb + 16, hb0,       off0, off1, acc, lds);
        full_chunk<2>(v4, w4, woff, cb + 20, hb0 + HCH, off0, off1, acc, lds);
      }
      __syncthreads(); buf ^= 1;
    }

    // Epilogue step: chunk 12 (phase 0): j = 48,49,50.
    stage_next();                        // next round's unit 0 (dead at t=1, harmless)
    if (act) {
      const float* hb = hbuf + buf * UNIT;
      const float4 e0a = *reinterpret_cast<const float4*>(hb + off0);
      const float4 e0b = *reinterpret_cast<const float4*>(hb + off1);
      const float4 e1a = *reinterpret_cast<const float4*>(hb + 512 + off0);
      const float4 e1b = *reinterpret_cast<const float4*>(hb + 512 + off1);
      const float4 e2a = *reinterpret_cast<const float4*>(hb + 1024 + off0);
      const float4 e2b = *reinterpret_cast<const float4*>(hb + 1024 + off1);
      fma_jtap<0, 0>(v4, w4, e0a, e0b, acc);
      fma_jtap<0, 1>(v4, w4, e1a, e1b, acc);
      fma_jtap<0, 2>(v4, w4, e2a, e2b, acc);
    }
    __syncthreads(); buf ^= 1;
  }

  // ---- Reduce the 4 wave partials (waves 1..3 -> LDS inp region, wave 0 adds & stores)
  // (trailing __syncthreads above orders all inp-tile reads before the overwrite)
  if (s > 0) {
    float* p = &lds[((s - 1) * 64 + ty * NTX + tx) * R];
#pragma unroll
    for (int rx = 0; rx < R; ++rx) p[rx] = acc[rx];
  }
  __syncthreads();
  if (s == 0) {
#pragma unroll
    for (int g = 0; g < 3; ++g) {
      const float* p = &lds[(g * 64 + ty * NTX + tx) * R];
#pragma unroll
      for (int rx = 0; rx < R; ++rx) acc[rx] += p[rx];
    }
    float* o = ws + (size_t)half * OUTN + (((size_t)(b * NC + c)) * HH + yg) * WW + xg;
    *reinterpret_cast<float4*>(o)     = make_float4(acc[0], acc[1], acc[2], acc[3]);
    *reinterpret_cast<float4*>(o + 4) = make_float4(acc[4], acc[5], acc[6], acc[7]);
  }
}

// Sum the two i-half partials into the output. 98304 float4 elements.
__global__ __launch_bounds__(256)
void sum_halves(const float4* __restrict__ a, const float4* __restrict__ b,
                float4* __restrict__ o)
{
  const int i = blockIdx.x * 256 + threadIdx.x;   // grid sized exactly
  const float4 x = a[i], y = b[i];
  o[i] = make_float4(x.x + y.x, x.y + y.y, x.z + y.z, x.w + y.w);
}

extern "C" void kernel_launch(void* const* d_in, const int* in_sizes, int n_in,
                              void* d_out, int out_size, void* d_ws, size_t ws_size,
                              hipStream_t stream) {
  const float* inp   = (const float*)d_in[0];
  const float* vert  = (const float*)d_in[1];
  const float* horiz = (const float*)d_in[2];
  float* out = (float*)d_out;
  float* ws  = (float*)d_ws;                      // needs 2 * 393216 floats = 3.15 MB

  dim3 grid(WW / TILE_W, HH / TILE_H, 2 * NB * NC);   // 4 x 32 x 12 = 1536 blocks
  sepconv_kernel<<<grid, NTHREADS, 0, stream>>>(inp, vert, horiz, ws);

  const int n4 = OUTN / 4;                        // 98304
  sum_halves<<<n4 / 256, 256, 0, stream>>>(
      (const float4*)ws, (const float4*)(ws + OUTN), (float4*)out);
}